// Round 12
// baseline (93.094 us; speedup 1.0000x reference)
//
#include <hip/hip_runtime.h>

// Histogram1D: triangular-kernel soft histogram, 100 bins over [0,1], row-normalized.
// x: [32, 1048576] f32. out: [32, 100] f32.
//
// Formulation (validated R3-R11): U = x*25600+128; iU=(int)U; r=iU>>8 in [0,100];
// cell(uint32) += 0x10000 | (iU&255)  (N in hi16, sum(floor(256w)) in lo16);
// counts[b] = N[b+1] - (W[b+1]-W[b])/256.  Native ds_add_u32 atomics (R11).
//
// Round-12: INSTRUMENTED ROUND. The harness's 75us poison-fill dispatches have
// hidden our hist kernel from rocprof's top-5 since R3; five pipe models in a
// row mispredicted. This round repeats the hist main loop REPEAT=4x (norm
// divides partials by 4 -> output identical to float rounding) so hist
// ~100us ranks #1 in top-5 and we finally read VALUBusy / Occupancy /
// FETCH_SIZE / LDS_BANK_CONFLICT for the real kernel. The 4x-scaling is also
// a memory-vs-compute decomposition: passes 2-4 are L3-warm, so
// hist(4x) ~ 4*hist(1x) => compute/DS/latency-bound; hist(4x) << 4*hist(1x)
// => pass-1 memory/latency dominated. Geometry unchanged from R11.

#define BINS 100
#define ROWS 101
#define BATCH 32
#define NPER 1048576
#define TPB 256
#define WAVES 4
#define COLS 16
#define BPR 48                         // blocks per row
#define GRID (BATCH * BPR)             // 1536 = 6 per CU, all resident
#define NF4_ROW (NPER / 4)             // 262144 float4 per row
#define STRIDE (BPR * TPB)             // 12288 f4 grid stride
#define HCELLS (WAVES * ROWS * COLS)   // 6464 dwords = 25.9 KB
#define REPEAT 4                       // diagnostic repeat (divided out in norm)

__global__ __launch_bounds__(TPB, 6) void hist_kernel(const float* __restrict__ x,
                                                      float* __restrict__ partial) {
    __shared__ uint32_t h[HCELLS];
    const int tid = threadIdx.x;

    uint4* h4 = reinterpret_cast<uint4*>(h);
    for (int i = tid; i < HCELLS / 4; i += TPB) h4[i] = make_uint4(0, 0, 0, 0);
    __syncthreads();

    const int row  = blockIdx.x / BPR;
    const int jblk = blockIdx.x % BPR;
    const int wave = tid >> 6;
    const int col  = (tid & 63) >> 2;            // 4 lanes share a column
    uint32_t* hw = h + wave * (ROWS * COLS) + col;

    const float4* src = reinterpret_cast<const float4*>(x + (size_t)row * NPER);
#pragma unroll 1
    for (int rep = 0; rep < REPEAT; ++rep) {
        for (int i = jblk * TPB + tid; i < NF4_ROW; i += STRIDE) {
            float4 v = src[i];
            float vv[4] = {v.x, v.y, v.z, v.w};
#pragma unroll
            for (int e = 0; e < 4; ++e) {
                float U = __builtin_fmaf(vv[e], 25600.0f, 128.0f);  // 256*(x*100+0.5)
                int  iU = (int)U;                                   // 128..25728
                int   r = iU >> 8;                                  // row 0..100
                uint32_t inc = 0x10000u | (uint32_t)(iU & 255);     // N=1 | Wfix
                atomicAdd(&hw[r * COLS], inc);   // native ds_add_u32, no return
            }
        }
    }
    __syncthreads();

    // Stage 1: per-(wave,row) sums over 16 cols (404 tasks; rotated col).
    // W-field carry check at REPEAT=4: mean 216 hits/(wave,row), carry needs
    // ~516 (W-sum >= 65536) -> ~20 sigma above mean, safe.
    uint32_t s0 = 0, s1 = 0;
    const int a0 = tid, a1 = tid + TPB;
    {
        int w = a0 / ROWS, r = a0 - w * ROWS;
        const uint32_t* base = h + w * (ROWS * COLS) + r * COLS;
        uint32_t s = 0;
#pragma unroll
        for (int c = 0; c < COLS; ++c) s += base[(c + tid) & (COLS - 1)];
        s0 = s;
    }
    if (a1 < WAVES * ROWS) {
        int w = a1 / ROWS, r = a1 - w * ROWS;
        const uint32_t* base = h + w * (ROWS * COLS) + r * COLS;
        uint32_t s = 0;
#pragma unroll
        for (int c = 0; c < COLS; ++c) s += base[(c + tid) & (COLS - 1)];
        s1 = s;
    }
    __syncthreads();
    // Stage 2: unpack task sums into reused h: N at [task], W at [512+task].
    h[a0] = s0 >> 16;
    h[512 + a0] = s0 & 0xFFFFu;
    if (a1 < WAVES * ROWS) { h[a1] = s1 >> 16; h[512 + a1] = s1 & 0xFFFFu; }
    __syncthreads();
    // Stage 3: per-row totals across the 4 waves.
    if (tid < ROWS) {
        uint32_t N = h[tid] + h[101 + tid] + h[202 + tid] + h[303 + tid];
        uint32_t W = h[512 + tid] + h[613 + tid] + h[714 + tid] + h[815 + tid];
        h[1024 + tid] = N;
        h[1536 + tid] = W;
    }
    __syncthreads();
    // Stage 4: counts[b] = (N[b+1] - (W[b+1]-W[b])/256) / REPEAT -> partial.
    if (tid < BINS) {
        float N1 = (float)h[1024 + tid + 1];
        float W1 = (float)h[1536 + tid + 1];
        float W0 = (float)h[1536 + tid];
        partial[blockIdx.x * BINS + tid] =
            (N1 + (W0 - W1) * (1.0f / 256.0f)) * (1.0f / REPEAT);
    }
}

// Reduce 48 partials per row, normalize, write all of d_out (no init needed).
__global__ __launch_bounds__(128) void norm_kernel(const float* __restrict__ partial,
                                                   float* __restrict__ out) {
    __shared__ float sarr[2];
    const int row = blockIdx.x;
    const int t   = threadIdx.x;
    float cnt = 0.0f;
    if (t < BINS) {
        const float* p = partial + (size_t)row * BPR * BINS + t;
#pragma unroll
        for (int j = 0; j < BPR; ++j) cnt += p[j * BINS];
    }
    float s = cnt;
#pragma unroll
    for (int off = 32; off > 0; off >>= 1) s += __shfl_down(s, off);
    if ((t & 63) == 0) sarr[t >> 6] = s;
    __syncthreads();
    const float total = sarr[0] + sarr[1];
    if (t < BINS) {
        out[row * BINS + t] = 0.01f * cnt / (0.01f * total + 1e-5f);
    }
}

extern "C" void kernel_launch(void* const* d_in, const int* in_sizes, int n_in,
                              void* d_out, int out_size, void* d_ws, size_t ws_size,
                              hipStream_t stream) {
    const float* x = (const float*)d_in[0];
    float* out = (float*)d_out;
    float* partial = (float*)d_ws;     // 1536*100*4 = 614.4 KB

    hist_kernel<<<GRID, TPB, 0, stream>>>(x, partial);
    norm_kernel<<<BATCH, 128, 0, stream>>>(partial, out);
}

// Round 13
// 38.312 us; speedup vs baseline: 2.4299x; 2.4299x over previous
//
#include <hip/hip_runtime.h>

// Histogram1D: triangular-kernel soft histogram, 100 bins over [0,1], row-normalized.
// x: [32, 1048576] f32. out: [32, 100] f32.
//
// Formulation (validated R3-R12): U = x*25600+128; iU=(int)U; r=iU>>8 in [0,100];
// cell(uint32) += 0x10000 | (iU&255)  (N in hi16, sum(floor(256w)) in lo16);
// counts[b] = N[b+1] - (W[b+1]-W[b])/256.  Native ds_add_u32 atomics (R11).
//
// R12 instrumented findings: 66K cyc/CU/pass wall; ds_add scattered ~32cyc/
// wave-instr; 17% bank-conflict cycles (quad layout's bank = f(r&1) variance);
// VALU 19%, HBM 30% -> DS-atomic path and/or blended L3+HBM read path limit.
//
// Round-13 (two independent fixes, attribute by delta):
//  a) CONFLICT-FREE ATOMIC BANKING: pair-share, [wave][row][32 cols];
//     bank = col = lane>>1 exactly, INDEPENDENT of r -> always 2 lanes/bank
//     (free per m136); the 17% conflict cycles vanish. LDS 51.7KB -> 3
//     blocks/CU (12 waves) - enough, atomics have no DS dependency chain.
//  b) NON-TEMPORAL LOADS: input is single-use streaming; NT bypasses L3/L2
//     so reads go straight HBM (~7 TB/s write-side proven by harness fills)
//     instead of the measured 4.9 TB/s blended L3+HBM path.

#define BINS 100
#define ROWS 101
#define BATCH 32
#define NPER 1048576
#define TPB 256
#define WAVES 4
#define COLS 32
#define BPR 24                         // blocks per row
#define GRID (BATCH * BPR)             // 768 = 3 per CU, all resident
#define NF4_ROW (NPER / 4)             // 262144 float4 per row
#define STRIDE (BPR * TPB)             // 6144 f4 grid stride
#define HCELLS (WAVES * ROWS * COLS)   // 12928 dwords = 51.7 KB

typedef float f32x4 __attribute__((ext_vector_type(4)));

__global__ __launch_bounds__(TPB, 3) void hist_kernel(const float* __restrict__ x,
                                                      float* __restrict__ partial) {
    __shared__ uint32_t h[HCELLS];
    const int tid = threadIdx.x;

    uint4* h4 = reinterpret_cast<uint4*>(h);
    for (int i = tid; i < HCELLS / 4; i += TPB) h4[i] = make_uint4(0, 0, 0, 0);
    __syncthreads();

    const int row  = blockIdx.x / BPR;
    const int jblk = blockIdx.x % BPR;
    const int wave = tid >> 6;
    const int col  = (tid & 63) >> 1;            // 2 lanes share a column
    uint32_t* hw = h + wave * (ROWS * COLS) + col;

    const f32x4* src = reinterpret_cast<const f32x4*>(x + (size_t)row * NPER);
    for (int i = jblk * TPB + tid; i < NF4_ROW; i += STRIDE) {
        f32x4 v = __builtin_nontemporal_load(&src[i]);   // single-use stream
#pragma unroll
        for (int e = 0; e < 4; ++e) {
            float U = __builtin_fmaf(v[e], 25600.0f, 128.0f);   // 256*(x*100+0.5)
            int  iU = (int)U;                                   // 128..25728
            int   r = iU >> 8;                                  // row 0..100
            uint32_t inc = 0x10000u | (uint32_t)(iU & 255);     // N=1 | Wfix
            atomicAdd(&hw[r * COLS], inc);       // ds_add_u32, bank = col always
        }
    }
    __syncthreads();

    // Stage 1: per-(wave,row) sums over 32 cols (404 tasks; rotated col).
    // W-field carry: mean 108 hits/(wave,row), carry needs ~516 -> safe.
    uint32_t s0 = 0, s1 = 0;
    const int a0 = tid, a1 = tid + TPB;
    {
        int w = a0 / ROWS, r = a0 - w * ROWS;
        const uint32_t* base = h + w * (ROWS * COLS) + r * COLS;
        uint32_t s = 0;
#pragma unroll
        for (int c = 0; c < COLS; ++c) s += base[(c + tid) & (COLS - 1)];
        s0 = s;
    }
    if (a1 < WAVES * ROWS) {
        int w = a1 / ROWS, r = a1 - w * ROWS;
        const uint32_t* base = h + w * (ROWS * COLS) + r * COLS;
        uint32_t s = 0;
#pragma unroll
        for (int c = 0; c < COLS; ++c) s += base[(c + tid) & (COLS - 1)];
        s1 = s;
    }
    __syncthreads();
    // Stage 2: unpack task sums into reused h: N at [task], W at [512+task].
    h[a0] = s0 >> 16;
    h[512 + a0] = s0 & 0xFFFFu;
    if (a1 < WAVES * ROWS) { h[a1] = s1 >> 16; h[512 + a1] = s1 & 0xFFFFu; }
    __syncthreads();
    // Stage 3: per-row totals across the 4 waves.
    if (tid < ROWS) {
        uint32_t N = h[tid] + h[101 + tid] + h[202 + tid] + h[303 + tid];
        uint32_t W = h[512 + tid] + h[613 + tid] + h[714 + tid] + h[815 + tid];
        h[1024 + tid] = N;
        h[1536 + tid] = W;
    }
    __syncthreads();
    // Stage 4: counts[b] = N[b+1] - (W[b+1]-W[b])/256 -> partial store.
    if (tid < BINS) {
        float N1 = (float)h[1024 + tid + 1];
        float W1 = (float)h[1536 + tid + 1];
        float W0 = (float)h[1536 + tid];
        partial[blockIdx.x * BINS + tid] = N1 + (W0 - W1) * (1.0f / 256.0f);
    }
}

// Reduce 24 partials per row, normalize, write all of d_out (no init needed).
__global__ __launch_bounds__(128) void norm_kernel(const float* __restrict__ partial,
                                                   float* __restrict__ out) {
    __shared__ float sarr[2];
    const int row = blockIdx.x;
    const int t   = threadIdx.x;
    float cnt = 0.0f;
    if (t < BINS) {
        const float* p = partial + (size_t)row * BPR * BINS + t;
#pragma unroll
        for (int j = 0; j < BPR; ++j) cnt += p[j * BINS];
    }
    float s = cnt;
#pragma unroll
    for (int off = 32; off > 0; off >>= 1) s += __shfl_down(s, off);
    if ((t & 63) == 0) sarr[t >> 6] = s;
    __syncthreads();
    const float total = sarr[0] + sarr[1];
    if (t < BINS) {
        out[row * BINS + t] = 0.01f * cnt / (0.01f * total + 1e-5f);
    }
}

extern "C" void kernel_launch(void* const* d_in, const int* in_sizes, int n_in,
                              void* d_out, int out_size, void* d_ws, size_t ws_size,
                              hipStream_t stream) {
    const float* x = (const float*)d_in[0];
    float* out = (float*)d_out;
    float* partial = (float*)d_ws;     // 768*100*4 = 307.2 KB

    hist_kernel<<<GRID, TPB, 0, stream>>>(x, partial);
    norm_kernel<<<BATCH, 128, 0, stream>>>(partial, out);
}

// Round 14
// 30.912 us; speedup vs baseline: 3.0116x; 1.2394x over previous
//
#include <hip/hip_runtime.h>

// Histogram1D: triangular-kernel soft histogram, 100 bins over [0,1], row-normalized.
// x: [32, 1048576] f32. out: [32, 100] f32.
//
// Formulation (validated R3-R13): U = x*25600+128; iU=(int)U; r=iU>>8 in [0,100];
// cell(uint32) += 0x10000 | (iU&255)  (N in hi16, sum(floor(256w)) in lo16);
// counts[b] = N[b+1] - (W[b+1]-W[b])/256.  Native ds_add_u32 atomics (R11).
//
// R12 (instrumented) pinned the wall: 66K cyc/CU/pass; ds_add ~27cyc base
// + 5.5cyc/instr bank-conflict tax (11K cyc/CU, from quad layout's
// bank = col + 16*(r&1)); OR co-limiting blended read path at 4.9 TB/s.
// R13 (NT + banking together) regressed -> NT loads reverted (bypassing
// L2/L3 killed the blend and request coalescing); confound lesson applied.
//
// Round-14: ISOLATE the conflict term. Pair-share conflict-free banking:
// [wave][row][32 cols]; bank = col = lane>>1 exactly, INDEPENDENT of r ->
// always 2 lanes/bank (free, m136). LDS 51.7KB -> 3 blocks/CU; safe for
// fire-and-forget atomics (no RMW chain; R7~R10 showed occupancy-null).
// Cached f32x4 loads (no NT). Everything else identical to R11 (best, 32.5).
// Outcome decides R15: win => conflicts were real; null => 4.9TB/s read
// path is the wall; regression => occupancy-sensitive, revert to quad.

#define BINS 100
#define ROWS 101
#define BATCH 32
#define NPER 1048576
#define TPB 256
#define WAVES 4
#define COLS 32
#define BPR 24                         // blocks per row
#define GRID (BATCH * BPR)             // 768 = 3 per CU, all resident
#define NF4_ROW (NPER / 4)             // 262144 float4 per row
#define STRIDE (BPR * TPB)             // 6144 f4 grid stride
#define HCELLS (WAVES * ROWS * COLS)   // 12928 dwords = 51.7 KB

typedef float f32x4 __attribute__((ext_vector_type(4)));

__global__ __launch_bounds__(TPB, 3) void hist_kernel(const float* __restrict__ x,
                                                      float* __restrict__ partial) {
    __shared__ uint32_t h[HCELLS];
    const int tid = threadIdx.x;

    uint4* h4 = reinterpret_cast<uint4*>(h);
    for (int i = tid; i < HCELLS / 4; i += TPB) h4[i] = make_uint4(0, 0, 0, 0);
    __syncthreads();

    const int row  = blockIdx.x / BPR;
    const int jblk = blockIdx.x % BPR;
    const int wave = tid >> 6;
    const int col  = (tid & 63) >> 1;            // 2 lanes share a column
    uint32_t* hw = h + wave * (ROWS * COLS) + col;

    const f32x4* src = reinterpret_cast<const f32x4*>(x + (size_t)row * NPER);
    for (int i = jblk * TPB + tid; i < NF4_ROW; i += STRIDE) {
        f32x4 v = src[i];                        // cached vector load (no NT)
#pragma unroll
        for (int e = 0; e < 4; ++e) {
            float U = __builtin_fmaf(v[e], 25600.0f, 128.0f);   // 256*(x*100+0.5)
            int  iU = (int)U;                                   // 128..25728
            int   r = iU >> 8;                                  // row 0..100
            uint32_t inc = 0x10000u | (uint32_t)(iU & 255);     // N=1 | Wfix
            atomicAdd(&hw[r * COLS], inc);       // ds_add_u32, bank = lane>>1 always
        }
    }
    __syncthreads();

    // Stage 1: per-(wave,row) sums over 32 cols (404 tasks; rotated col).
    // W-field carry: mean 108 hits/(wave,row), carry needs ~516 -> ~40 sigma, safe.
    uint32_t s0 = 0, s1 = 0;
    const int a0 = tid, a1 = tid + TPB;
    {
        int w = a0 / ROWS, r = a0 - w * ROWS;
        const uint32_t* base = h + w * (ROWS * COLS) + r * COLS;
        uint32_t s = 0;
#pragma unroll
        for (int c = 0; c < COLS; ++c) s += base[(c + tid) & (COLS - 1)];
        s0 = s;
    }
    if (a1 < WAVES * ROWS) {
        int w = a1 / ROWS, r = a1 - w * ROWS;
        const uint32_t* base = h + w * (ROWS * COLS) + r * COLS;
        uint32_t s = 0;
#pragma unroll
        for (int c = 0; c < COLS; ++c) s += base[(c + tid) & (COLS - 1)];
        s1 = s;
    }
    __syncthreads();
    // Stage 2: unpack task sums into reused h: N at [task], W at [512+task].
    h[a0] = s0 >> 16;
    h[512 + a0] = s0 & 0xFFFFu;
    if (a1 < WAVES * ROWS) { h[a1] = s1 >> 16; h[512 + a1] = s1 & 0xFFFFu; }
    __syncthreads();
    // Stage 3: per-row totals across the 4 waves.
    if (tid < ROWS) {
        uint32_t N = h[tid] + h[101 + tid] + h[202 + tid] + h[303 + tid];
        uint32_t W = h[512 + tid] + h[613 + tid] + h[714 + tid] + h[815 + tid];
        h[1024 + tid] = N;
        h[1536 + tid] = W;
    }
    __syncthreads();
    // Stage 4: counts[b] = N[b+1] - (W[b+1]-W[b])/256 -> partial store.
    if (tid < BINS) {
        float N1 = (float)h[1024 + tid + 1];
        float W1 = (float)h[1536 + tid + 1];
        float W0 = (float)h[1536 + tid];
        partial[blockIdx.x * BINS + tid] = N1 + (W0 - W1) * (1.0f / 256.0f);
    }
}

// Reduce 24 partials per row, normalize, write all of d_out (no init needed).
__global__ __launch_bounds__(128) void norm_kernel(const float* __restrict__ partial,
                                                   float* __restrict__ out) {
    __shared__ float sarr[2];
    const int row = blockIdx.x;
    const int t   = threadIdx.x;
    float cnt = 0.0f;
    if (t < BINS) {
        const float* p = partial + (size_t)row * BPR * BINS + t;
#pragma unroll
        for (int j = 0; j < BPR; ++j) cnt += p[j * BINS];
    }
    float s = cnt;
#pragma unroll
    for (int off = 32; off > 0; off >>= 1) s += __shfl_down(s, off);
    if ((t & 63) == 0) sarr[t >> 6] = s;
    __syncthreads();
    const float total = sarr[0] + sarr[1];
    if (t < BINS) {
        out[row * BINS + t] = 0.01f * cnt / (0.01f * total + 1e-5f);
    }
}

extern "C" void kernel_launch(void* const* d_in, const int* in_sizes, int n_in,
                              void* d_out, int out_size, void* d_ws, size_t ws_size,
                              hipStream_t stream) {
    const float* x = (const float*)d_in[0];
    float* out = (float*)d_out;
    float* partial = (float*)d_ws;     // 768*100*4 = 307.2 KB

    hist_kernel<<<GRID, TPB, 0, stream>>>(x, partial);
    norm_kernel<<<BATCH, 128, 0, stream>>>(partial, out);
}